// Round 8
// baseline (200.350 us; speedup 1.0000x reference)
//
#include <hip/hip_runtime.h>
#include <hip/hip_bf16.h>

#define EMB 1024
#define NEXP 8
#define NH 1024
#define N_GU 2048
#define TOPK 2

#define BK 64
#define KTILES 16      // 1024 / 64

#define BMg 256        // gate_up tile
#define BNg 256
#define MAXT256 40

#define BMd 128        // down tile
#define BNd 128
#define MAXT128 72

typedef __attribute__((ext_vector_type(4))) float f32x4;
typedef __attribute__((ext_vector_type(8))) short s16x8;
typedef __attribute__((ext_vector_type(4))) short s16x4;

typedef __attribute__((address_space(3))) unsigned int lds_u32;
typedef __attribute__((address_space(1))) const unsigned int glb_u32;

__device__ __forceinline__ void gl_lds16(const void* g, void* l) {
  __builtin_amdgcn_global_load_lds((glb_u32*)g, (lds_u32*)l, 16, 0, 0);
}

__device__ __forceinline__ unsigned short f2bf(float f) {
  union { float f; unsigned int u; } a; a.f = f;
  unsigned int u = a.u;
  unsigned int r = (u + 0x7FFFu + ((u >> 16) & 1u)) >> 16;
  return (unsigned short)r;
}

// bijective chunked XCD swizzle (m204)
__device__ __forceinline__ int xcd_swz(int bid, int nwg) {
  int q = nwg >> 3, r = nwg & 7;
  int xcd = bid & 7, pos = bid >> 3;
  int base = (xcd < r) ? xcd * (q + 1) : r * (q + 1) + (xcd - r) * q;
  return base + pos;
}

// ---------------- fused fp32 -> bf16 conversion ----------------
__global__ void convert_all(const float* __restrict__ a, unsigned short* __restrict__ oa, int n4a,
                            const float* __restrict__ b, unsigned short* __restrict__ ob, int n4b,
                            const float* __restrict__ c, unsigned short* __restrict__ oc, int n4c) {
  int tot = n4a + n4b + n4c;
  for (int i = blockIdx.x * blockDim.x + threadIdx.x; i < tot; i += gridDim.x * blockDim.x) {
    const float* src; unsigned short* dst; int k;
    if (i < n4a) { src = a; dst = oa; k = i; }
    else if (i < n4a + n4b) { src = b; dst = ob; k = i - n4a; }
    else { src = c; dst = oc; k = i - n4a - n4b; }
    float4 v = ((const float4*)src)[k];
    s16x4 o;
    o[0] = (short)f2bf(v.x);
    o[1] = (short)f2bf(v.y);
    o[2] = (short)f2bf(v.z);
    o[3] = (short)f2bf(v.w);
    ((s16x4*)dst)[k] = o;
  }
}

// ---------------- router ----------------
__global__ void router_topk(const float* __restrict__ x, const float* __restrict__ rw,
                            const float* __restrict__ rb, int T,
                            int* __restrict__ tokE, float* __restrict__ tokW) {
  int gwid = (blockIdx.x * blockDim.x + threadIdx.x) >> 6;
  int lane = threadIdx.x & 63;
  if (gwid >= T) return;
  const float* h = x + (size_t)gwid * EMB;
  float hreg[16];
  #pragma unroll
  for (int i = 0; i < 16; ++i) hreg[i] = h[lane + 64 * i];
  float sc[NEXP];
  #pragma unroll
  for (int e = 0; e < NEXP; ++e) {
    const float* w = rw + e * EMB;
    float s = 0.f;
    #pragma unroll
    for (int i = 0; i < 16; ++i) s += hreg[i] * w[lane + 64 * i];
    #pragma unroll
    for (int off = 32; off > 0; off >>= 1) s += __shfl_xor(s, off);
    sc[e] = s + rb[e];
  }
  if (lane == 0) {
    int e0 = 0; float v0 = sc[0];
    #pragma unroll
    for (int e = 1; e < NEXP; ++e) if (sc[e] > v0) { v0 = sc[e]; e0 = e; }
    int e1 = -1; float v1 = -3.0e38f;
    #pragma unroll
    for (int e = 0; e < NEXP; ++e) { if (e == e0) continue; if (sc[e] > v1) { v1 = sc[e]; e1 = e; } }
    float ex = __expf(v1 - v0);
    float w0 = 1.f / (1.f + ex);
    float w1 = ex / (1.f + ex);
    tokE[gwid * 2] = e0; tokE[gwid * 2 + 1] = e1;
    tokW[gwid * 2] = w0; tokW[gwid * 2 + 1] = w1;
  }
}

// ---------------- histogram + offsets + BOTH tile maps ----------------
__global__ void count_meta(const int* __restrict__ tokE, int A,
                           int* __restrict__ offsets,
                           int* __restrict__ tm256, int* __restrict__ tm128) {
  __shared__ int hist[NEXP];
  int t = threadIdx.x;
  if (t < NEXP) hist[t] = 0;
  __syncthreads();
  for (int i = t; i < A; i += blockDim.x) atomicAdd(&hist[tokE[i]], 1);
  __syncthreads();
  if (t == 0) {
    int off = 0, nt2 = 0, nt1 = 0;
    for (int e = 0; e < NEXP; ++e) {
      offsets[e] = off;
      int c = hist[e];
      int n2 = (c + BMg - 1) / BMg;
      for (int k = 0; k < n2; ++k) {
        tm256[1 + nt2 * 3 + 0] = e;
        tm256[1 + nt2 * 3 + 1] = off + k * BMg;
        tm256[1 + nt2 * 3 + 2] = off + c;
        nt2++;
      }
      int n1 = (c + BMd - 1) / BMd;
      for (int k = 0; k < n1; ++k) {
        tm128[1 + nt1 * 3 + 0] = e;
        tm128[1 + nt1 * 3 + 1] = off + k * BMd;
        tm128[1 + nt1 * 3 + 2] = off + c;
        nt1++;
      }
      off += c;
    }
    offsets[NEXP] = off;
    tm256[0] = nt2;
    tm128[0] = nt1;
  }
}

// ---------------- scatter with wave-aggregated atomics ----------------
__global__ void scatter_tokens(const int* __restrict__ tokE, const int* __restrict__ offsets,
                               int* __restrict__ fill, int* __restrict__ rows,
                               int* __restrict__ apos, int A) {
  int i = blockIdx.x * blockDim.x + threadIdx.x;
  int lane = threadIdx.x & 63;
  int e = tokE[i];
  int p = -1;
  #pragma unroll
  for (int ex = 0; ex < NEXP; ++ex) {
    unsigned long long mask = __ballot(e == ex);
    if (mask) {
      int leader = __ffsll(mask) - 1;
      int cnt = __popcll(mask);
      int base = 0;
      if (lane == leader) base = atomicAdd(&fill[ex], cnt);
      base = __shfl(base, leader);
      if (e == ex) {
        int rank = __popcll(mask & ((1ull << lane) - 1ull));
        p = offsets[ex] + base + rank;
      }
    }
  }
  rows[p] = i >> 1;
  apos[i] = p;
}

// ---------------- grouped GEMM 1 (256x256, 8 waves): gathered x @ gate_up_w^T + SwiGLU ----------------
__global__ __launch_bounds__(512, 2) void gemm_gate_up(
    const unsigned short* __restrict__ xb,
    const unsigned short* __restrict__ gub,
    const float* __restrict__ gu_bias,
    const int* __restrict__ rows,
    const int* __restrict__ tilemeta,
    unsigned short* __restrict__ hact) {
  __shared__ __align__(16) short As[BMg * BK];   // 32 KB
  __shared__ __align__(16) short Bs[BNg * BK];   // 32 KB
  int wg = xcd_swz(blockIdx.x, gridDim.x);
  int tileid = wg >> 3;          // y = wg & 7 fast axis (N_GU/256 = 8)
  int n0 = (wg & 7) * BNg;
  int nt = tilemeta[0];
  if (tileid >= nt) return;
  int e    = tilemeta[1 + tileid * 3 + 0];
  int m0   = tilemeta[1 + tileid * 3 + 1];
  int mEnd = tilemeta[1 + tileid * 3 + 2];

  int t = threadIdx.x;
  int lane = t & 63;
  int wid = t >> 6;              // 0..7
  int wr = wid >> 2;             // 0..1  (row half: 128 rows each)
  int wc = wid & 3;              // 0..3  (col quarter: 64 cols each)

  // staging: instr q covers rows q*64 + wid*8 .. +8; lane l -> row +(l>>3), LDS chunk (l&7)
  // SOURCE pre-swizzle (rule #21): global chunk (l&7) ^ (row&7), row&7 = (l>>3)&7
  int srow = lane >> 3;
  int scol = (((lane & 7) ^ (srow & 7)) * 8);
  const unsigned short* ga[4];
  const unsigned short* gb[4];
  int dstoff[4];
  #pragma unroll
  for (int q = 0; q < 4; ++q) {
    int rt = q * 64 + wid * 8 + srow;              // tile row 0..255
    int ai = m0 + rt; if (ai >= mEnd) ai = mEnd - 1;
    ga[q] = xb + (size_t)rows[ai] * EMB + scol;
    gb[q] = gub + ((size_t)e * N_GU + n0 + rt) * EMB + scol;
    dstoff[q] = (q * 64 + wid * 8) * BK;           // wave-uniform
  }

  int fr = lane & 15;
  int q8 = (lane >> 4) * 8;
  int rsw = (fr & 7) << 3;       // read-side swizzle (elem), row&7 = fr&7

  f32x4 acc[8][4];
  #pragma unroll
  for (int i = 0; i < 8; ++i)
    #pragma unroll
    for (int j = 0; j < 4; ++j) acc[i][j] = (f32x4){0.f, 0.f, 0.f, 0.f};

  for (int tk = 0; tk < KTILES; ++tk) {
    int k0 = tk * BK;
    __syncthreads();             // buffer free
    #pragma unroll
    for (int q = 0; q < 4; ++q) {
      gl_lds16(ga[q] + k0, &As[dstoff[q]]);
      gl_lds16(gb[q] + k0, &Bs[dstoff[q]]);
    }
    __syncthreads();             // implicit vmcnt(0) drain: tile visible
    #pragma unroll
    for (int kk = 0; kk < BK; kk += 32) {
      s16x8 a[8], b[4];
      #pragma unroll
      for (int i = 0; i < 8; ++i)
        a[i] = *(const s16x8*)(&As[(wr * 128 + i * 16 + fr) * BK + ((kk + q8) ^ rsw)]);
      #pragma unroll
      for (int j = 0; j < 4; ++j)
        b[j] = *(const s16x8*)(&Bs[(wc * 64 + j * 16 + fr) * BK + ((kk + q8) ^ rsw)]);
      #pragma unroll
      for (int i = 0; i < 8; ++i)
        #pragma unroll
        for (int j = 0; j < 4; ++j)
          acc[i][j] = __builtin_amdgcn_mfma_f32_16x16x32_bf16(a[i], b[j], acc[i][j], 0, 0, 0);
    }
  }

  // epilogue: bias + SwiGLU (pair even/odd N via shfl_xor 1) -> bf16 hact
  const float* bias_e = gu_bias + (size_t)e * N_GU;
  int rbase = m0 + wr * 128 + ((lane >> 4) * 4);
  #pragma unroll
  for (int i = 0; i < 8; ++i) {
    #pragma unroll
    for (int j = 0; j < 4; ++j) {
      int n = n0 + wc * 64 + j * 16 + fr;
      float v[4], o[4];
      #pragma unroll
      for (int r = 0; r < 4; ++r) v[r] = acc[i][j][r] + bias_e[n];
      #pragma unroll
      for (int r = 0; r < 4; ++r) o[r] = __shfl_xor(v[r], 1);
      if ((lane & 1) == 0) {
        int outc = n >> 1;
        #pragma unroll
        for (int r = 0; r < 4; ++r) {
          int pos = rbase + i * 16 + r;
          if (pos < mEnd) {
            float g = v[r], u = o[r];
            float gc = fminf(fmaxf(g, -7.f), 7.f);
            float uc = fminf(fmaxf(u, -7.f), 7.f);
            float sig = 1.f / (1.f + __expf(-1.702f * g));
            float act = gc * sig * (uc + 1.f);
            hact[(size_t)pos * NH + outc] = f2bf(act);
          }
        }
      }
    }
  }
}

// ---------------- grouped GEMM 2 (128x128, 4 waves): hact @ down_w^T -> y ----------------
__global__ __launch_bounds__(256, 4) void gemm_down(
    const unsigned short* __restrict__ hact,
    const unsigned short* __restrict__ dwb,
    const int* __restrict__ tilemeta,
    float* __restrict__ y) {
  __shared__ __align__(16) short As[BMd * BK];
  __shared__ __align__(16) short Bs[BNd * BK];
  int wg = xcd_swz(blockIdx.x, gridDim.x);
  int tileid = wg >> 3;          // y = wg & 7 fast axis (EMB/128 = 8)
  int n0 = (wg & 7) * BNd;
  int nt = tilemeta[0];
  if (tileid >= nt) return;
  int e    = tilemeta[1 + tileid * 3 + 0];
  int m0   = tilemeta[1 + tileid * 3 + 1];
  int mEnd = tilemeta[1 + tileid * 3 + 2];

  int t = threadIdx.x;
  int lane = t & 63;
  int wid = t >> 6;
  int wr = wid >> 1, wc = wid & 1;

  int srow = lane >> 3;
  int scol = (((lane & 7) ^ (srow & 7)) * 8);
  const unsigned short* ga[4];
  const unsigned short* gb[4];
  int dstoff[4];
  #pragma unroll
  for (int q = 0; q < 4; ++q) {
    int rt = wid * 32 + q * 8 + srow;
    int ai = m0 + rt; if (ai >= mEnd) ai = mEnd - 1;
    ga[q] = hact + (size_t)ai * NH + scol;
    gb[q] = dwb + ((size_t)e * EMB + n0 + rt) * NH + scol;
    dstoff[q] = (wid * 32 + q * 8) * BK;
  }

  int fr = lane & 15;
  int q8 = (lane >> 4) * 8;
  int rsw = (fr & 7) << 3;

  f32x4 acc[4][4];
  #pragma unroll
  for (int i = 0; i < 4; ++i)
    #pragma unroll
    for (int j = 0; j < 4; ++j) acc[i][j] = (f32x4){0.f, 0.f, 0.f, 0.f};

  for (int tk = 0; tk < KTILES; ++tk) {
    int k0 = tk * BK;
    __syncthreads();
    #pragma unroll
    for (int q = 0; q < 4; ++q) {
      gl_lds16(ga[q] + k0, &As[dstoff[q]]);
      gl_lds16(gb[q] + k0, &Bs[dstoff[q]]);
    }
    __syncthreads();
    #pragma unroll
    for (int kk = 0; kk < BK; kk += 32) {
      s16x8 a[4], b[4];
      #pragma unroll
      for (int i = 0; i < 4; ++i)
        a[i] = *(const s16x8*)(&As[(wr * 64 + i * 16 + fr) * BK + ((kk + q8) ^ rsw)]);
      #pragma unroll
      for (int j = 0; j < 4; ++j)
        b[j] = *(const s16x8*)(&Bs[(wc * 64 + j * 16 + fr) * BK + ((kk + q8) ^ rsw)]);
      #pragma unroll
      for (int i = 0; i < 4; ++i)
        #pragma unroll
        for (int j = 0; j < 4; ++j)
          acc[i][j] = __builtin_amdgcn_mfma_f32_16x16x32_bf16(a[i], b[j], acc[i][j], 0, 0, 0);
    }
  }

  int rbase = m0 + wr * 64 + ((lane >> 4) * 4);
  #pragma unroll
  for (int i = 0; i < 4; ++i) {
    #pragma unroll
    for (int j = 0; j < 4; ++j) {
      int n = n0 + wc * 64 + j * 16 + fr;
      #pragma unroll
      for (int r = 0; r < 4; ++r) {
        int pos = rbase + i * 16 + r;
        if (pos < mEnd) y[(size_t)pos * EMB + n] = acc[i][j][r];
      }
    }
  }
}

// ---------------- final combine ----------------
__global__ void combine_out(const float* __restrict__ y, const float* __restrict__ down_b,
                            const int* __restrict__ tokE, const float* __restrict__ tokW,
                            const int* __restrict__ apos, float* __restrict__ out, int T) {
  int i = blockIdx.x * blockDim.x + threadIdx.x;
  int tot = T * (EMB / 4);
  if (i >= tot) return;
  int tok = i >> 8;
  int c = i & 255;
  int e0 = tokE[tok * 2], e1 = tokE[tok * 2 + 1];
  float w0 = tokW[tok * 2], w1 = tokW[tok * 2 + 1];
  int p0 = apos[tok * 2], p1 = apos[tok * 2 + 1];
  float4 y0 = ((const float4*)(y + (size_t)p0 * EMB))[c];
  float4 y1 = ((const float4*)(y + (size_t)p1 * EMB))[c];
  float4 b0 = ((const float4*)(down_b + (size_t)e0 * EMB))[c];
  float4 b1 = ((const float4*)(down_b + (size_t)e1 * EMB))[c];
  float4 o;
  o.x = w0 * (y0.x + b0.x) + w1 * (y1.x + b1.x);
  o.y = w0 * (y0.y + b0.y) + w1 * (y1.y + b1.y);
  o.z = w0 * (y0.z + b0.z) + w1 * (y1.z + b1.z);
  o.w = w0 * (y0.w + b0.w) + w1 * (y1.w + b1.w);
  ((float4*)out)[i] = o;
}

extern "C" void kernel_launch(void* const* d_in, const int* in_sizes, int n_in,
                              void* d_out, int out_size, void* d_ws, size_t ws_size,
                              hipStream_t stream) {
  const float* x   = (const float*)d_in[0];
  const float* rw  = (const float*)d_in[1];
  const float* rb  = (const float*)d_in[2];
  const float* guw = (const float*)d_in[3];
  const float* gub = (const float*)d_in[4];
  const float* dw  = (const float*)d_in[5];
  const float* db  = (const float*)d_in[6];
  float* out = (float*)d_out;

  int T = in_sizes[0] / EMB;   // 4096
  int A = T * TOPK;            // 8192

  char* ws = (char*)d_ws;
  size_t off = 0;
  auto alloc = [&](size_t bytes) -> void* {
    void* p = ws + off;
    off = (off + bytes + 255) & ~((size_t)255);
    return p;
  };
  unsigned short* xb   = (unsigned short*)alloc((size_t)T * EMB * 2);
  unsigned short* guwb = (unsigned short*)alloc((size_t)NEXP * N_GU * EMB * 2);
  unsigned short* dwb  = (unsigned short*)alloc((size_t)NEXP * EMB * NH * 2);
  unsigned short* hact = (unsigned short*)alloc((size_t)A * NH * 2);
  float* y             = (float*)alloc((size_t)A * EMB * 4);
  int*   tokE    = (int*)alloc((size_t)A * 4);
  float* tokW    = (float*)alloc((size_t)A * 4);
  int*   apos    = (int*)alloc((size_t)A * 4);
  int*   rowsArr = (int*)alloc((size_t)A * 4);
  int*   fill    = (int*)alloc(NEXP * 4);
  int*   offsets = (int*)alloc((NEXP + 1) * 4);
  int*   tm256   = (int*)alloc((1 + MAXT256 * 3) * 4);
  int*   tm128   = (int*)alloc((1 + MAXT128 * 3) * 4);

  hipMemsetAsync(fill, 0, NEXP * 4, stream);

  int n4x = T * EMB / 4;
  int n4g = NEXP * N_GU * EMB / 4;
  int n4d = NEXP * EMB * NH / 4;
  convert_all<<<2048, 256, 0, stream>>>(x, xb, n4x, guw, guwb, n4g, dw, dwb, n4d);

  router_topk<<<T / 4, 256, 0, stream>>>(x, rw, rb, T, tokE, tokW);
  count_meta<<<1, 1024, 0, stream>>>(tokE, A, offsets, tm256, tm128);
  scatter_tokens<<<A / 256, 256, 0, stream>>>(tokE, offsets, fill, rowsArr, apos, A);

  gemm_gate_up<<<MAXT256 * (N_GU / BNg), 512, 0, stream>>>(xb, guwb, gub, rowsArr, tm256, hact);
  gemm_down<<<MAXT128 * (EMB / BNd), 256, 0, stream>>>(hact, dwb, tm128, y);

  combine_out<<<(T * EMB / 4 + 255) / 256, 256, 0, stream>>>(y, db, tokE, tokW, apos, out, T);
}

// Round 9
// 173.743 us; speedup vs baseline: 1.1531x; 1.1531x over previous
//
#include <hip/hip_runtime.h>
#include <hip/hip_bf16.h>

#define EMB 1024
#define NEXP 8
#define NH 1024
#define N_GU 2048
#define TOPK 2

// gate_up: 256x128 tile, BK=32 sub-tiles, 2-slot ring
#define BMg 256
#define BNg 128
#define BKs 32
#define NSUB 32
#define MAXT256 40

// down: proven R6 config (128x128, BK=64, swizzled)
#define BMd 128
#define BNd 128
#define BKd 64
#define KTILESd 16
#define MAXT128 72

typedef __attribute__((ext_vector_type(4))) float f32x4;
typedef __attribute__((ext_vector_type(8))) short s16x8;
typedef __attribute__((ext_vector_type(4))) short s16x4;

typedef __attribute__((address_space(3))) unsigned int lds_u32;
typedef __attribute__((address_space(1))) const unsigned int glb_u32;

__device__ __forceinline__ void gl_lds16(const void* g, void* l) {
  __builtin_amdgcn_global_load_lds((glb_u32*)g, (lds_u32*)l, 16, 0, 0);
}

__device__ __forceinline__ unsigned short f2bf(float f) {
  union { float f; unsigned int u; } a; a.f = f;
  unsigned int u = a.u;
  unsigned int r = (u + 0x7FFFu + ((u >> 16) & 1u)) >> 16;
  return (unsigned short)r;
}

// bijective chunked XCD swizzle (m204)
__device__ __forceinline__ int xcd_swz(int bid, int nwg) {
  int q = nwg >> 3, r = nwg & 7;
  int xcd = bid & 7, pos = bid >> 3;
  int base = (xcd < r) ? xcd * (q + 1) : r * (q + 1) + (xcd - r) * q;
  return base + pos;
}

// ---------------- fused fp32 -> bf16 conversion ----------------
__global__ void convert_all(const float* __restrict__ a, unsigned short* __restrict__ oa, int n4a,
                            const float* __restrict__ b, unsigned short* __restrict__ ob, int n4b,
                            const float* __restrict__ c, unsigned short* __restrict__ oc, int n4c) {
  int tot = n4a + n4b + n4c;
  for (int i = blockIdx.x * blockDim.x + threadIdx.x; i < tot; i += gridDim.x * blockDim.x) {
    const float* src; unsigned short* dst; int k;
    if (i < n4a) { src = a; dst = oa; k = i; }
    else if (i < n4a + n4b) { src = b; dst = ob; k = i - n4a; }
    else { src = c; dst = oc; k = i - n4a - n4b; }
    float4 v = ((const float4*)src)[k];
    s16x4 o;
    o[0] = (short)f2bf(v.x);
    o[1] = (short)f2bf(v.y);
    o[2] = (short)f2bf(v.z);
    o[3] = (short)f2bf(v.w);
    ((s16x4*)dst)[k] = o;
  }
}

// ---------------- router ----------------
__global__ void router_topk(const float* __restrict__ x, const float* __restrict__ rw,
                            const float* __restrict__ rb, int T,
                            int* __restrict__ tokE, float* __restrict__ tokW) {
  int gwid = (blockIdx.x * blockDim.x + threadIdx.x) >> 6;
  int lane = threadIdx.x & 63;
  if (gwid >= T) return;
  const float* h = x + (size_t)gwid * EMB;
  float hreg[16];
  #pragma unroll
  for (int i = 0; i < 16; ++i) hreg[i] = h[lane + 64 * i];
  float sc[NEXP];
  #pragma unroll
  for (int e = 0; e < NEXP; ++e) {
    const float* w = rw + e * EMB;
    float s = 0.f;
    #pragma unroll
    for (int i = 0; i < 16; ++i) s += hreg[i] * w[lane + 64 * i];
    #pragma unroll
    for (int off = 32; off > 0; off >>= 1) s += __shfl_xor(s, off);
    sc[e] = s + rb[e];
  }
  if (lane == 0) {
    int e0 = 0; float v0 = sc[0];
    #pragma unroll
    for (int e = 1; e < NEXP; ++e) if (sc[e] > v0) { v0 = sc[e]; e0 = e; }
    int e1 = -1; float v1 = -3.0e38f;
    #pragma unroll
    for (int e = 0; e < NEXP; ++e) { if (e == e0) continue; if (sc[e] > v1) { v1 = sc[e]; e1 = e; } }
    float ex = __expf(v1 - v0);
    float w0 = 1.f / (1.f + ex);
    float w1 = ex / (1.f + ex);
    tokE[gwid * 2] = e0; tokE[gwid * 2 + 1] = e1;
    tokW[gwid * 2] = w0; tokW[gwid * 2 + 1] = w1;
  }
}

// ---------------- histogram + offsets + BOTH tile maps ----------------
__global__ void count_meta(const int* __restrict__ tokE, int A,
                           int* __restrict__ offsets,
                           int* __restrict__ tm256, int* __restrict__ tm128) {
  __shared__ int hist[NEXP];
  int t = threadIdx.x;
  if (t < NEXP) hist[t] = 0;
  __syncthreads();
  for (int i = t; i < A; i += blockDim.x) atomicAdd(&hist[tokE[i]], 1);
  __syncthreads();
  if (t == 0) {
    int off = 0, nt2 = 0, nt1 = 0;
    for (int e = 0; e < NEXP; ++e) {
      offsets[e] = off;
      int c = hist[e];
      int n2 = (c + BMg - 1) / BMg;
      for (int k = 0; k < n2; ++k) {
        tm256[1 + nt2 * 3 + 0] = e;
        tm256[1 + nt2 * 3 + 1] = off + k * BMg;
        tm256[1 + nt2 * 3 + 2] = off + c;
        nt2++;
      }
      int n1 = (c + BMd - 1) / BMd;
      for (int k = 0; k < n1; ++k) {
        tm128[1 + nt1 * 3 + 0] = e;
        tm128[1 + nt1 * 3 + 1] = off + k * BMd;
        tm128[1 + nt1 * 3 + 2] = off + c;
        nt1++;
      }
      off += c;
    }
    offsets[NEXP] = off;
    tm256[0] = nt2;
    tm128[0] = nt1;
  }
}

// ---------------- scatter with wave-aggregated atomics ----------------
__global__ void scatter_tokens(const int* __restrict__ tokE, const int* __restrict__ offsets,
                               int* __restrict__ fill, int* __restrict__ rows,
                               int* __restrict__ apos, int A) {
  int i = blockIdx.x * blockDim.x + threadIdx.x;
  int lane = threadIdx.x & 63;
  int e = tokE[i];
  int p = -1;
  #pragma unroll
  for (int ex = 0; ex < NEXP; ++ex) {
    unsigned long long mask = __ballot(e == ex);
    if (mask) {
      int leader = __ffsll(mask) - 1;
      int cnt = __popcll(mask);
      int base = 0;
      if (lane == leader) base = atomicAdd(&fill[ex], cnt);
      base = __shfl(base, leader);
      if (e == ex) {
        int rank = __popcll(mask & ((1ull << lane) - 1ull));
        p = offsets[ex] + base + rank;
      }
    }
  }
  rows[p] = i >> 1;
  apos[i] = p;
}

// ---------------- grouped GEMM 1 (256x128, BK=32 ring, 8 waves): x @ gate_up_w^T + SwiGLU ----------------
__global__ __launch_bounds__(512, 2) void gemm_gate_up(
    const unsigned short* __restrict__ xb,
    const unsigned short* __restrict__ gub,
    const float* __restrict__ gu_bias,
    const int* __restrict__ rows,
    const int* __restrict__ tilemeta,
    unsigned short* __restrict__ hact) {
  __shared__ __align__(16) short As[2][BMg * BKs];   // 2 x 16 KB
  __shared__ __align__(16) short Bs[2][BNg * BKs];   // 2 x 8 KB   (48 KB total)
  int wg = xcd_swz(blockIdx.x, gridDim.x);
  int tileid = wg >> 4;          // n-fast: wg & 15 (N_GU/128 = 16)
  int n0 = (wg & 15) * BNg;
  int nt = tilemeta[0];
  if (tileid >= nt) return;
  int e    = tilemeta[1 + tileid * 3 + 0];
  int m0   = tilemeta[1 + tileid * 3 + 1];
  int mEnd = tilemeta[1 + tileid * 3 + 2];

  int t = threadIdx.x;
  int lane = t & 63;
  int wid = t >> 6;              // 0..7
  int wr = wid >> 1;             // 0..3 : rows wr*64
  int wc = wid & 1;              // 0..1 : cols wc*64

  // staging: lane covers row +(l>>2), 16B chunk (l&3) of a 16-row x 64B region per instr.
  // A: instr q (0,1) -> rows q*128 + wid*16 .. +16.  B: rows wid*16 .. +16. Linear LDS (BK=32: conflict-free).
  int srow = lane >> 2;
  int chnk = (lane & 3) * 8;     // element offset
  const unsigned short* gaP[2];
  int dstA[2];
  #pragma unroll
  for (int q = 0; q < 2; ++q) {
    int rt = q * 128 + wid * 16 + srow;
    int ai = m0 + rt; if (ai >= mEnd) ai = mEnd - 1;
    gaP[q] = xb + (size_t)rows[ai] * EMB + chnk;
    dstA[q] = (q * 128 + wid * 16) * BKs;
  }
  const unsigned short* gbP = gub + ((size_t)e * N_GU + n0 + wid * 16 + srow) * EMB + chnk;
  int dstB = (wid * 16) * BKs;

  int fr = lane & 15;
  int kq = (lane >> 4) * 8;      // k element offset

  f32x4 acc[4][4];
  #pragma unroll
  for (int i = 0; i < 4; ++i)
    #pragma unroll
    for (int j = 0; j < 4; ++j) acc[i][j] = (f32x4){0.f, 0.f, 0.f, 0.f};

  // STAGE(s): 3 gl_lds into slot s&1
  auto STAGE = [&](int s) {
    int k0 = s * BKs;
    int sl = s & 1;
    gl_lds16(gaP[0] + k0, &As[sl][dstA[0]]);
    gl_lds16(gaP[1] + k0, &As[sl][dstA[1]]);
    gl_lds16(gbP    + k0, &Bs[sl][dstB]);
  };

  // prologue: slot0 <- sub 0, slot1 <- sub 1; certify sub 0 landed
  STAGE(0);
  STAGE(1);
  asm volatile("s_waitcnt vmcnt(3)" ::: "memory");
  __builtin_amdgcn_s_barrier();

  for (int s = 0; s < NSUB; ++s) {
    int sl = s & 1;
    s16x8 a[4], b[4];
    #pragma unroll
    for (int i = 0; i < 4; ++i)
      a[i] = *(const s16x8*)(&As[sl][(wr * 64 + i * 16 + fr) * BKs + kq]);
    #pragma unroll
    for (int j = 0; j < 4; ++j)
      b[j] = *(const s16x8*)(&Bs[sl][(wc * 64 + j * 16 + fr) * BKs + kq]);
    asm volatile("" ::: "memory");
    __builtin_amdgcn_s_barrier();            // all waves issued reads of slot sl
    if (s + 2 < NSUB) STAGE(s + 2);          // overwrite slot sl; lands >=300cy later -> safe
    __builtin_amdgcn_s_setprio(1);
    #pragma unroll
    for (int i = 0; i < 4; ++i)
      #pragma unroll
      for (int j = 0; j < 4; ++j)
        acc[i][j] = __builtin_amdgcn_mfma_f32_16x16x32_bf16(a[i], b[j], acc[i][j], 0, 0, 0);
    __builtin_amdgcn_s_setprio(0);
    if (s < NSUB - 2)       asm volatile("s_waitcnt vmcnt(3)" ::: "memory");  // s+1 landed, s+2 in flight
    else if (s == NSUB - 2) asm volatile("s_waitcnt vmcnt(0)" ::: "memory");  // last tile landed
    if (s < NSUB - 1) __builtin_amdgcn_s_barrier();
  }

  // epilogue: bias + SwiGLU (pair even/odd N via shfl_xor 1) -> bf16 hact
  const float* bias_e = gu_bias + (size_t)e * N_GU;
  int rbase = m0 + wr * 64 + ((lane >> 4) * 4);
  #pragma unroll
  for (int i = 0; i < 4; ++i) {
    #pragma unroll
    for (int j = 0; j < 4; ++j) {
      int n = n0 + wc * 64 + j * 16 + fr;
      float v[4], o[4];
      #pragma unroll
      for (int r = 0; r < 4; ++r) v[r] = acc[i][j][r] + bias_e[n];
      #pragma unroll
      for (int r = 0; r < 4; ++r) o[r] = __shfl_xor(v[r], 1);
      if ((lane & 1) == 0) {
        int outc = n >> 1;
        #pragma unroll
        for (int r = 0; r < 4; ++r) {
          int pos = rbase + i * 16 + r;
          if (pos < mEnd) {
            float g = v[r], u = o[r];
            float gc = fminf(fmaxf(g, -7.f), 7.f);
            float uc = fminf(fmaxf(u, -7.f), 7.f);
            float sig = 1.f / (1.f + __expf(-1.702f * g));
            float act = gc * sig * (uc + 1.f);
            hact[(size_t)pos * NH + outc] = f2bf(act);
          }
        }
      }
    }
  }
}

// ---------------- grouped GEMM 2 (R6-proven 128x128, BK=64, swizzled): hact @ down_w^T -> y ----------------
__global__ __launch_bounds__(256, 4) void gemm_down(
    const unsigned short* __restrict__ hact,
    const unsigned short* __restrict__ dwb,
    const int* __restrict__ tilemeta,
    float* __restrict__ y) {
  __shared__ __align__(16) short As[BMd * BKd];
  __shared__ __align__(16) short Bs[BNd * BKd];
  int wg = xcd_swz(blockIdx.x, gridDim.x);
  int tileid = wg >> 3;          // n-fast (EMB/128 = 8)
  int n0 = (wg & 7) * BNd;
  int nt = tilemeta[0];
  if (tileid >= nt) return;
  int e    = tilemeta[1 + tileid * 3 + 0];
  int m0   = tilemeta[1 + tileid * 3 + 1];
  int mEnd = tilemeta[1 + tileid * 3 + 2];

  int t = threadIdx.x;
  int lane = t & 63;
  int wid = t >> 6;
  int wr = wid >> 1, wc = wid & 1;

  int srow = lane >> 3;
  int scol = (((lane & 7) ^ (srow & 7)) * 8);
  const unsigned short* ga[4];
  const unsigned short* gb[4];
  int dstoff[4];
  #pragma unroll
  for (int q = 0; q < 4; ++q) {
    int rt = wid * 32 + q * 8 + srow;
    int ai = m0 + rt; if (ai >= mEnd) ai = mEnd - 1;
    ga[q] = hact + (size_t)ai * NH + scol;
    gb[q] = dwb + ((size_t)e * EMB + n0 + rt) * NH + scol;
    dstoff[q] = (wid * 32 + q * 8) * BKd;
  }

  int fr = lane & 15;
  int q8 = (lane >> 4) * 8;
  int rsw = (fr & 7) << 3;

  f32x4 acc[4][4];
  #pragma unroll
  for (int i = 0; i < 4; ++i)
    #pragma unroll
    for (int j = 0; j < 4; ++j) acc[i][j] = (f32x4){0.f, 0.f, 0.f, 0.f};

  for (int tk = 0; tk < KTILESd; ++tk) {
    int k0 = tk * BKd;
    __syncthreads();
    #pragma unroll
    for (int q = 0; q < 4; ++q) {
      gl_lds16(ga[q] + k0, &As[dstoff[q]]);
      gl_lds16(gb[q] + k0, &Bs[dstoff[q]]);
    }
    __syncthreads();
    #pragma unroll
    for (int kk = 0; kk < BKd; kk += 32) {
      s16x8 a[4], b[4];
      #pragma unroll
      for (int i = 0; i < 4; ++i)
        a[i] = *(const s16x8*)(&As[(wr * 64 + i * 16 + fr) * BKd + ((kk + q8) ^ rsw)]);
      #pragma unroll
      for (int j = 0; j < 4; ++j)
        b[j] = *(const s16x8*)(&Bs[(wc * 64 + j * 16 + fr) * BKd + ((kk + q8) ^ rsw)]);
      #pragma unroll
      for (int i = 0; i < 4; ++i)
        #pragma unroll
        for (int j = 0; j < 4; ++j)
          acc[i][j] = __builtin_amdgcn_mfma_f32_16x16x32_bf16(a[i], b[j], acc[i][j], 0, 0, 0);
    }
  }

  int rbase = m0 + wr * 64 + ((lane >> 4) * 4);
  #pragma unroll
  for (int i = 0; i < 4; ++i) {
    #pragma unroll
    for (int j = 0; j < 4; ++j) {
      int n = n0 + wc * 64 + j * 16 + fr;
      #pragma unroll
      for (int r = 0; r < 4; ++r) {
        int pos = rbase + i * 16 + r;
        if (pos < mEnd) y[(size_t)pos * EMB + n] = acc[i][j][r];
      }
    }
  }
}

// ---------------- final combine ----------------
__global__ void combine_out(const float* __restrict__ y, const float* __restrict__ down_b,
                            const int* __restrict__ tokE, const float* __restrict__ tokW,
                            const int* __restrict__ apos, float* __restrict__ out, int T) {
  int i = blockIdx.x * blockDim.x + threadIdx.x;
  int tot = T * (EMB / 4);
  if (i >= tot) return;
  int tok = i >> 8;
  int c = i & 255;
  int e0 = tokE[tok * 2], e1 = tokE[tok * 2 + 1];
  float w0 = tokW[tok * 2], w1 = tokW[tok * 2 + 1];
  int p0 = apos[tok * 2], p1 = apos[tok * 2 + 1];
  float4 y0 = ((const float4*)(y + (size_t)p0 * EMB))[c];
  float4 y1 = ((const float4*)(y + (size_t)p1 * EMB))[c];
  float4 b0 = ((const float4*)(down_b + (size_t)e0 * EMB))[c];
  float4 b1 = ((const float4*)(down_b + (size_t)e1 * EMB))[c];
  float4 o;
  o.x = w0 * (y0.x + b0.x) + w1 * (y1.x + b1.x);
  o.y = w0 * (y0.y + b0.y) + w1 * (y1.y + b1.y);
  o.z = w0 * (y0.z + b0.z) + w1 * (y1.z + b1.z);
  o.w = w0 * (y0.w + b0.w) + w1 * (y1.w + b1.w);
  ((float4*)out)[i] = o;
}

extern "C" void kernel_launch(void* const* d_in, const int* in_sizes, int n_in,
                              void* d_out, int out_size, void* d_ws, size_t ws_size,
                              hipStream_t stream) {
  const float* x   = (const float*)d_in[0];
  const float* rw  = (const float*)d_in[1];
  const float* rb  = (const float*)d_in[2];
  const float* guw = (const float*)d_in[3];
  const float* gub = (const float*)d_in[4];
  const float* dw  = (const float*)d_in[5];
  const float* db  = (const float*)d_in[6];
  float* out = (float*)d_out;

  int T = in_sizes[0] / EMB;   // 4096
  int A = T * TOPK;            // 8192

  char* ws = (char*)d_ws;
  size_t off = 0;
  auto alloc = [&](size_t bytes) -> void* {
    void* p = ws + off;
    off = (off + bytes + 255) & ~((size_t)255);
    return p;
  };
  unsigned short* xb   = (unsigned short*)alloc((size_t)T * EMB * 2);
  unsigned short* guwb = (unsigned short*)alloc((size_t)NEXP * N_GU * EMB * 2);
  unsigned short* dwb  = (unsigned short*)alloc((size_t)NEXP * EMB * NH * 2);
  unsigned short* hact = (unsigned short*)alloc((size_t)A * NH * 2);
  float* y             = (float*)alloc((size_t)A * EMB * 4);
  int*   tokE    = (int*)alloc((size_t)A * 4);
  float* tokW    = (float*)alloc((size_t)A * 4);
  int*   apos    = (int*)alloc((size_t)A * 4);
  int*   rowsArr = (int*)alloc((size_t)A * 4);
  int*   fill    = (int*)alloc(NEXP * 4);
  int*   offsets = (int*)alloc((NEXP + 1) * 4);
  int*   tm256   = (int*)alloc((1 + MAXT256 * 3) * 4);
  int*   tm128   = (int*)alloc((1 + MAXT128 * 3) * 4);

  hipMemsetAsync(fill, 0, NEXP * 4, stream);

  int n4x = T * EMB / 4;
  int n4g = NEXP * N_GU * EMB / 4;
  int n4d = NEXP * EMB * NH / 4;
  convert_all<<<2048, 256, 0, stream>>>(x, xb, n4x, guw, guwb, n4g, dw, dwb, n4d);

  router_topk<<<T / 4, 256, 0, stream>>>(x, rw, rb, T, tokE, tokW);
  count_meta<<<1, 1024, 0, stream>>>(tokE, A, offsets, tm256, tm128);
  scatter_tokens<<<A / 256, 256, 0, stream>>>(tokE, offsets, fill, rowsArr, apos, A);

  gemm_gate_up<<<MAXT256 * (N_GU / BNg), 512, 0, stream>>>(xb, guwb, gub, rowsArr, tm256, hact);
  gemm_down<<<MAXT128 * (EMB / BNd), 256, 0, stream>>>(hact, dwb, tm128, y);

  combine_out<<<(T * EMB / 4 + 255) / 256, 256, 0, stream>>>(y, db, tokE, tokW, apos, out, T);
}

// Round 10
// 154.015 us; speedup vs baseline: 1.3008x; 1.1281x over previous
//
#include <hip/hip_runtime.h>
#include <hip/hip_bf16.h>

#define EMB 1024
#define NEXP 8
#define NH 1024
#define N_GU 2048
#define TOPK 2

#define BM 128
#define BN 128
#define BK 64
#define KTILES 16      // 1024 / 64
#define MAXTILES 72

typedef __attribute__((ext_vector_type(4))) float f32x4;
typedef __attribute__((ext_vector_type(8))) short s16x8;
typedef __attribute__((ext_vector_type(4))) short s16x4;

typedef __attribute__((address_space(3))) unsigned int lds_u32;
typedef __attribute__((address_space(1))) const unsigned int glb_u32;

__device__ __forceinline__ void gl_lds16(const void* g, void* l) {
  __builtin_amdgcn_global_load_lds((glb_u32*)g, (lds_u32*)l, 16, 0, 0);
}

__device__ __forceinline__ unsigned short f2bf(float f) {
  union { float f; unsigned int u; } a; a.f = f;
  unsigned int u = a.u;
  unsigned int r = (u + 0x7FFFu + ((u >> 16) & 1u)) >> 16;
  return (unsigned short)r;
}

__device__ __forceinline__ float b2f(unsigned short h) {
  union { unsigned int u; float f; } a;
  a.u = ((unsigned int)h) << 16;
  return a.f;
}

// bijective chunked XCD swizzle (m204)
__device__ __forceinline__ int xcd_swz(int bid, int nwg) {
  int q = nwg >> 3, r = nwg & 7;
  int xcd = bid & 7, pos = bid >> 3;
  int base = (xcd < r) ? xcd * (q + 1) : r * (q + 1) + (xcd - r) * q;
  return base + pos;
}

// ---------------- fused router + fp32->bf16 conversion (block-role partition) ----------------
__global__ void convert_router(const float* __restrict__ x, unsigned short* __restrict__ xb, int n4x,
                               const float* __restrict__ guw, unsigned short* __restrict__ guwb, int n4g,
                               const float* __restrict__ dw, unsigned short* __restrict__ dwb, int n4d,
                               const float* __restrict__ rw, const float* __restrict__ rb, int T,
                               int* __restrict__ tokE, float* __restrict__ tokW) {
  int nr = T / 4;   // router blocks (4 waves = 4 tokens each)
  if ((int)blockIdx.x < nr) {
    int gwid = blockIdx.x * 4 + (threadIdx.x >> 6);
    int lane = threadIdx.x & 63;
    if (gwid >= T) return;
    const float* h = x + (size_t)gwid * EMB;
    float hreg[16];
    #pragma unroll
    for (int i = 0; i < 16; ++i) hreg[i] = h[lane + 64 * i];
    float sc[NEXP];
    #pragma unroll
    for (int e = 0; e < NEXP; ++e) {
      const float* w = rw + e * EMB;
      float s = 0.f;
      #pragma unroll
      for (int i = 0; i < 16; ++i) s += hreg[i] * w[lane + 64 * i];
      #pragma unroll
      for (int off = 32; off > 0; off >>= 1) s += __shfl_xor(s, off);
      sc[e] = s + rb[e];
    }
    if (lane == 0) {
      int e0 = 0; float v0 = sc[0];
      #pragma unroll
      for (int e = 1; e < NEXP; ++e) if (sc[e] > v0) { v0 = sc[e]; e0 = e; }
      int e1 = -1; float v1 = -3.0e38f;
      #pragma unroll
      for (int e = 0; e < NEXP; ++e) { if (e == e0) continue; if (sc[e] > v1) { v1 = sc[e]; e1 = e; } }
      float ex = __expf(v1 - v0);
      float w0 = 1.f / (1.f + ex);
      float w1 = ex / (1.f + ex);
      tokE[gwid * 2] = e0; tokE[gwid * 2 + 1] = e1;
      tokW[gwid * 2] = w0; tokW[gwid * 2 + 1] = w1;
    }
  } else {
    int tot = n4x + n4g + n4d;
    int base = (blockIdx.x - nr) * blockDim.x + threadIdx.x;
    int stride = (gridDim.x - nr) * blockDim.x;
    for (int i = base; i < tot; i += stride) {
      const float* src; unsigned short* dst; int k;
      if (i < n4x) { src = x; dst = xb; k = i; }
      else if (i < n4x + n4g) { src = guw; dst = guwb; k = i - n4x; }
      else { src = dw; dst = dwb; k = i - n4x - n4g; }
      float4 v = ((const float4*)src)[k];
      s16x4 o;
      o[0] = (short)f2bf(v.x);
      o[1] = (short)f2bf(v.y);
      o[2] = (short)f2bf(v.z);
      o[3] = (short)f2bf(v.w);
      ((s16x4*)dst)[k] = o;
    }
  }
}

// ---------------- histogram + offsets + tile map ----------------
__global__ void count_meta(const int* __restrict__ tokE, int A,
                           int* __restrict__ offsets, int* __restrict__ tilemeta) {
  __shared__ int hist[NEXP];
  int t = threadIdx.x;
  if (t < NEXP) hist[t] = 0;
  __syncthreads();
  for (int i = t; i < A; i += blockDim.x) atomicAdd(&hist[tokE[i]], 1);
  __syncthreads();
  if (t == 0) {
    int off = 0, nt = 0;
    for (int e = 0; e < NEXP; ++e) {
      offsets[e] = off;
      int c = hist[e];
      int ntile = (c + BM - 1) / BM;
      for (int k = 0; k < ntile; ++k) {
        tilemeta[1 + nt * 3 + 0] = e;
        tilemeta[1 + nt * 3 + 1] = off + k * BM;
        tilemeta[1 + nt * 3 + 2] = off + c;
        nt++;
      }
      off += c;
    }
    offsets[NEXP] = off;
    tilemeta[0] = nt;
  }
}

// ---------------- scatter with wave-aggregated atomics ----------------
__global__ void scatter_tokens(const int* __restrict__ tokE, const int* __restrict__ offsets,
                               int* __restrict__ fill, int* __restrict__ rows,
                               int* __restrict__ apos, int A) {
  int i = blockIdx.x * blockDim.x + threadIdx.x;
  int lane = threadIdx.x & 63;
  int e = tokE[i];
  int p = -1;
  #pragma unroll
  for (int ex = 0; ex < NEXP; ++ex) {
    unsigned long long mask = __ballot(e == ex);
    if (mask) {
      int leader = __ffsll(mask) - 1;
      int cnt = __popcll(mask);
      int base = 0;
      if (lane == leader) base = atomicAdd(&fill[ex], cnt);
      base = __shfl(base, leader);
      if (e == ex) {
        int rank = __popcll(mask & ((1ull << lane) - 1ull));
        p = offsets[ex] + base + rank;
      }
    }
  }
  rows[p] = i >> 1;
  apos[i] = p;
}

// ---------------- grouped GEMM 1: gathered x @ gate_up_w[e]^T, fused SwiGLU ----------------
// single-buffer 32KB LDS; cross-block overlap hides stage drain (m97/m114)
__global__ __launch_bounds__(256, 4) void gemm_gate_up(
    const unsigned short* __restrict__ xb,
    const unsigned short* __restrict__ gub,
    const float* __restrict__ gu_bias,
    const int* __restrict__ rows,
    const int* __restrict__ tilemeta,
    unsigned short* __restrict__ hact) {
  __shared__ __align__(16) short As[BM * BK];
  __shared__ __align__(16) short Bs[BN * BK];
  int wg = xcd_swz(blockIdx.x, gridDim.x);
  int tileid = wg >> 4;          // y = wg & 15 fast axis (A-tile reuse adjacency)
  int n0 = (wg & 15) * BN;
  int nt = tilemeta[0];
  if (tileid >= nt) return;
  int e    = tilemeta[1 + tileid * 3 + 0];
  int m0   = tilemeta[1 + tileid * 3 + 1];
  int mEnd = tilemeta[1 + tileid * 3 + 2];

  int t = threadIdx.x;
  int lane = t & 63;
  int wid = t >> 6;
  int wr = wid >> 1, wc = wid & 1;

  // staging: inst q covers rows wid*32+q*8..+8; lane l -> row +(l>>3), LDS chunk (l&7).
  // SOURCE pre-swizzle (rule #21): fetch global chunk (l&7) ^ (row&7).
  int srow = lane >> 3;
  int scol = (((lane & 7) ^ (srow & 7)) * 8);
  const unsigned short* ga[4];
  const unsigned short* gb[4];
  int dstoff[4];
  #pragma unroll
  for (int q = 0; q < 4; ++q) {
    int rt = wid * 32 + q * 8 + srow;
    int ai = m0 + rt; if (ai >= mEnd) ai = mEnd - 1;
    ga[q] = xb + (size_t)rows[ai] * EMB + scol;
    gb[q] = gub + ((size_t)e * N_GU + n0 + rt) * EMB + scol;
    dstoff[q] = (wid * 32 + q * 8) * BK;
  }

  int fr = lane & 15;
  int q8 = (lane >> 4) * 8;
  int rsw = (fr & 7) << 3;       // read-side swizzle (elem), row&7 = fr&7

  f32x4 acc[4][4];
  #pragma unroll
  for (int i = 0; i < 4; ++i)
    #pragma unroll
    for (int j = 0; j < 4; ++j) acc[i][j] = (f32x4){0.f, 0.f, 0.f, 0.f};

  for (int tk = 0; tk < KTILES; ++tk) {
    int k0 = tk * BK;
    __syncthreads();             // buffer free (previous compute done)
    #pragma unroll
    for (int q = 0; q < 4; ++q) {
      gl_lds16(ga[q] + k0, &As[dstoff[q]]);
      gl_lds16(gb[q] + k0, &Bs[dstoff[q]]);
    }
    __syncthreads();             // implicit vmcnt(0) drain: tile visible to all waves
    #pragma unroll
    for (int kk = 0; kk < BK; kk += 32) {
      s16x8 a[4], b[4];
      #pragma unroll
      for (int i = 0; i < 4; ++i)
        a[i] = *(const s16x8*)(&As[(wr * 64 + i * 16 + fr) * BK + ((kk + q8) ^ rsw)]);
      #pragma unroll
      for (int j = 0; j < 4; ++j)
        b[j] = *(const s16x8*)(&Bs[(wc * 64 + j * 16 + fr) * BK + ((kk + q8) ^ rsw)]);
      #pragma unroll
      for (int i = 0; i < 4; ++i)
        #pragma unroll
        for (int j = 0; j < 4; ++j)
          acc[i][j] = __builtin_amdgcn_mfma_f32_16x16x32_bf16(a[i], b[j], acc[i][j], 0, 0, 0);
    }
  }

  // epilogue: bias + SwiGLU (pair even/odd N via shfl_xor 1) -> bf16 hact
  const float* bias_e = gu_bias + (size_t)e * N_GU;
  int rbase = m0 + wr * 64 + ((lane >> 4) * 4);
  #pragma unroll
  for (int i = 0; i < 4; ++i) {
    #pragma unroll
    for (int j = 0; j < 4; ++j) {
      int n = n0 + wc * 64 + j * 16 + fr;
      float v[4], o[4];
      #pragma unroll
      for (int r = 0; r < 4; ++r) v[r] = acc[i][j][r] + bias_e[n];
      #pragma unroll
      for (int r = 0; r < 4; ++r) o[r] = __shfl_xor(v[r], 1);
      if ((lane & 1) == 0) {
        int outc = n >> 1;
        #pragma unroll
        for (int r = 0; r < 4; ++r) {
          int pos = rbase + i * 16 + r;
          if (pos < mEnd) {
            float g = v[r], u = o[r];
            float gc = fminf(fmaxf(g, -7.f), 7.f);
            float uc = fminf(fmaxf(u, -7.f), 7.f);
            float sig = 1.f / (1.f + __expf(-1.702f * g));
            float act = gc * sig * (uc + 1.f);
            hact[(size_t)pos * NH + outc] = f2bf(act);
          }
        }
      }
    }
  }
}

// ---------------- grouped GEMM 2: hact @ down_w[e]^T -> y (bf16) ----------------
__global__ __launch_bounds__(256, 4) void gemm_down(
    const unsigned short* __restrict__ hact,
    const unsigned short* __restrict__ dwb,
    const int* __restrict__ tilemeta,
    unsigned short* __restrict__ y) {
  __shared__ __align__(16) short As[BM * BK];
  __shared__ __align__(16) short Bs[BN * BK];
  int wg = xcd_swz(blockIdx.x, gridDim.x);
  int tileid = wg >> 3;          // y = wg & 7 fast axis
  int n0 = (wg & 7) * BN;
  int nt = tilemeta[0];
  if (tileid >= nt) return;
  int e    = tilemeta[1 + tileid * 3 + 0];
  int m0   = tilemeta[1 + tileid * 3 + 1];
  int mEnd = tilemeta[1 + tileid * 3 + 2];

  int t = threadIdx.x;
  int lane = t & 63;
  int wid = t >> 6;
  int wr = wid >> 1, wc = wid & 1;

  int srow = lane >> 3;
  int scol = (((lane & 7) ^ (srow & 7)) * 8);
  const unsigned short* ga[4];
  const unsigned short* gb[4];
  int dstoff[4];
  #pragma unroll
  for (int q = 0; q < 4; ++q) {
    int rt = wid * 32 + q * 8 + srow;
    int ai = m0 + rt; if (ai >= mEnd) ai = mEnd - 1;
    ga[q] = hact + (size_t)ai * NH + scol;
    gb[q] = dwb + ((size_t)e * EMB + n0 + rt) * NH + scol;
    dstoff[q] = (wid * 32 + q * 8) * BK;
  }

  int fr = lane & 15;
  int q8 = (lane >> 4) * 8;
  int rsw = (fr & 7) << 3;

  f32x4 acc[4][4];
  #pragma unroll
  for (int i = 0; i < 4; ++i)
    #pragma unroll
    for (int j = 0; j < 4; ++j) acc[i][j] = (f32x4){0.f, 0.f, 0.f, 0.f};

  for (int tk = 0; tk < KTILES; ++tk) {
    int k0 = tk * BK;
    __syncthreads();
    #pragma unroll
    for (int q = 0; q < 4; ++q) {
      gl_lds16(ga[q] + k0, &As[dstoff[q]]);
      gl_lds16(gb[q] + k0, &Bs[dstoff[q]]);
    }
    __syncthreads();
    #pragma unroll
    for (int kk = 0; kk < BK; kk += 32) {
      s16x8 a[4], b[4];
      #pragma unroll
      for (int i = 0; i < 4; ++i)
        a[i] = *(const s16x8*)(&As[(wr * 64 + i * 16 + fr) * BK + ((kk + q8) ^ rsw)]);
      #pragma unroll
      for (int j = 0; j < 4; ++j)
        b[j] = *(const s16x8*)(&Bs[(wc * 64 + j * 16 + fr) * BK + ((kk + q8) ^ rsw)]);
      #pragma unroll
      for (int i = 0; i < 4; ++i)
        #pragma unroll
        for (int j = 0; j < 4; ++j)
          acc[i][j] = __builtin_amdgcn_mfma_f32_16x16x32_bf16(a[i], b[j], acc[i][j], 0, 0, 0);
    }
  }

  int rbase = m0 + wr * 64 + ((lane >> 4) * 4);
  #pragma unroll
  for (int i = 0; i < 4; ++i) {
    #pragma unroll
    for (int j = 0; j < 4; ++j) {
      int n = n0 + wc * 64 + j * 16 + fr;
      #pragma unroll
      for (int r = 0; r < 4; ++r) {
        int pos = rbase + i * 16 + r;
        if (pos < mEnd) y[(size_t)pos * EMB + n] = f2bf(acc[i][j][r]);
      }
    }
  }
}

// ---------------- final combine (bf16 y) ----------------
__global__ void combine_out(const unsigned short* __restrict__ y, const float* __restrict__ down_b,
                            const int* __restrict__ tokE, const float* __restrict__ tokW,
                            const int* __restrict__ apos, float* __restrict__ out, int T) {
  int i = blockIdx.x * blockDim.x + threadIdx.x;
  int tot = T * (EMB / 4);
  if (i >= tot) return;
  int tok = i >> 8;
  int c = i & 255;
  int e0 = tokE[tok * 2], e1 = tokE[tok * 2 + 1];
  float w0 = tokW[tok * 2], w1 = tokW[tok * 2 + 1];
  int p0 = apos[tok * 2], p1 = apos[tok * 2 + 1];
  s16x4 v0 = ((const s16x4*)(y + (size_t)p0 * EMB))[c];
  s16x4 v1 = ((const s16x4*)(y + (size_t)p1 * EMB))[c];
  float4 b0 = ((const float4*)(down_b + (size_t)e0 * EMB))[c];
  float4 b1 = ((const float4*)(down_b + (size_t)e1 * EMB))[c];
  float4 o;
  o.x = w0 * (b2f((unsigned short)v0[0]) + b0.x) + w1 * (b2f((unsigned short)v1[0]) + b1.x);
  o.y = w0 * (b2f((unsigned short)v0[1]) + b0.y) + w1 * (b2f((unsigned short)v1[1]) + b1.y);
  o.z = w0 * (b2f((unsigned short)v0[2]) + b0.z) + w1 * (b2f((unsigned short)v1[2]) + b1.z);
  o.w = w0 * (b2f((unsigned short)v0[3]) + b0.w) + w1 * (b2f((unsigned short)v1[3]) + b1.w);
  ((float4*)out)[i] = o;
}

extern "C" void kernel_launch(void* const* d_in, const int* in_sizes, int n_in,
                              void* d_out, int out_size, void* d_ws, size_t ws_size,
                              hipStream_t stream) {
  const float* x   = (const float*)d_in[0];
  const float* rw  = (const float*)d_in[1];
  const float* rb  = (const float*)d_in[2];
  const float* guw = (const float*)d_in[3];
  const float* gub = (const float*)d_in[4];
  const float* dw  = (const float*)d_in[5];
  const float* db  = (const float*)d_in[6];
  float* out = (float*)d_out;

  int T = in_sizes[0] / EMB;   // 4096
  int A = T * TOPK;            // 8192

  char* ws = (char*)d_ws;
  size_t off = 0;
  auto alloc = [&](size_t bytes) -> void* {
    void* p = ws + off;
    off = (off + bytes + 255) & ~((size_t)255);
    return p;
  };
  unsigned short* xb   = (unsigned short*)alloc((size_t)T * EMB * 2);
  unsigned short* guwb = (unsigned short*)alloc((size_t)NEXP * N_GU * EMB * 2);
  unsigned short* dwb  = (unsigned short*)alloc((size_t)NEXP * EMB * NH * 2);
  unsigned short* hact = (unsigned short*)alloc((size_t)A * NH * 2);
  unsigned short* y    = (unsigned short*)alloc((size_t)A * EMB * 2);
  int*   tokE    = (int*)alloc((size_t)A * 4);
  float* tokW    = (float*)alloc((size_t)A * 4);
  int*   apos    = (int*)alloc((size_t)A * 4);
  int*   rowsArr = (int*)alloc((size_t)A * 4);
  int*   fill    = (int*)alloc(NEXP * 4);
  int*   offsets = (int*)alloc((NEXP + 1) * 4);
  int*   tilemeta= (int*)alloc((1 + MAXTILES * 3) * 4);

  hipMemsetAsync(fill, 0, NEXP * 4, stream);

  int n4x = T * EMB / 4;
  int n4g = NEXP * N_GU * EMB / 4;
  int n4d = NEXP * EMB * NH / 4;
  convert_router<<<T / 4 + 2048, 256, 0, stream>>>(x, xb, n4x, guw, guwb, n4g, dw, dwb, n4d,
                                                   rw, rb, T, tokE, tokW);

  count_meta<<<1, 1024, 0, stream>>>(tokE, A, offsets, tilemeta);
  scatter_tokens<<<A / 256, 256, 0, stream>>>(tokE, offsets, fill, rowsArr, apos, A);

  gemm_gate_up<<<MAXTILES * (N_GU / BN), 256, 0, stream>>>(xb, guwb, gub, rowsArr, tilemeta, hact);
  gemm_down<<<MAXTILES * (EMB / BN), 256, 0, stream>>>(hact, dwb, tilemeta, y);

  combine_out<<<(T * EMB / 4 + 255) / 256, 256, 0, stream>>>(y, db, tokE, tokW, apos, out, T);
}